// Round 1
// baseline (1309.474 us; speedup 1.0000x reference)
//
#include <hip/hip_runtime.h>
#include <math.h>

#define TOKENS 64          // tokens per block
#define KC 128             // k-chunk staged in LDS
#define DIM 4096           // hidden dim
#define NEXP 64            // experts
#define LDS_STRIDE (KC + 4)  // pad 4 floats: keeps 16B align, baseline-equivalent b128 bank pattern

// Block: 256 threads = 4 waves. Wave w handles experts [w*16, w*16+16); lane = token.
// K-loop: double-buffered LDS h-tile, one barrier per chunk, software-pipelined
// global loads. W accessed via wave-uniform pointers -> scalar loads.
__global__ __launch_bounds__(256, 1)
void topk_gate_kernel(const float* __restrict__ h, const float* __restrict__ W,
                      float* __restrict__ out, int n_tokens) {
    __shared__ float lds[2 * TOKENS * LDS_STRIDE];  // 16896 floats = 67.6 KB

    const int tid  = threadIdx.x;
    const int lane = tid & 63;
    // Force wave id into an SGPR so W address math is provably wave-uniform.
    const int wave = __builtin_amdgcn_readfirstlane(tid >> 6);
    const int t0   = blockIdx.x * TOKENS;

    const float* wbase = W + (size_t)wave * 16 * DIM;  // uniform

    float acc[16];
#pragma unroll
    for (int j = 0; j < 16; ++j) acc[j] = 0.0f;

    // ---- software-pipelined staging regs: 8 float4 per thread per chunk ----
    float4 st[8];
    // prologue: load chunk 0
#pragma unroll
    for (int r = 0; r < 8; ++r) {
        int flat = r * 256 + tid;
        int t = flat >> 5, q = flat & 31;                // 32 float4 per 128-float row
        st[r] = *(const float4*)(h + (size_t)(t0 + t) * DIM + 0 + q * 4);
    }

    const int NCHUNK = DIM / KC;  // 32
    for (int c = 0; c < NCHUNK; ++c) {
        const int kc = c * KC;
        float* buf = &lds[(c & 1) * TOKENS * LDS_STRIDE];

        // write staged regs -> LDS
#pragma unroll
        for (int r = 0; r < 8; ++r) {
            int flat = r * 256 + tid;
            int t = flat >> 5, q = flat & 31;
            *(float4*)(buf + t * LDS_STRIDE + q * 4) = st[r];
        }
        __syncthreads();

        // issue next chunk's global loads (overlap with compute below)
        if (c + 1 < NCHUNK) {
            const int kn = kc + KC;
#pragma unroll
            for (int r = 0; r < 8; ++r) {
                int flat = r * 256 + tid;
                int t = flat >> 5, q = flat & 31;
                st[r] = *(const float4*)(h + (size_t)(t0 + t) * DIM + kn + q * 4);
            }
        }

        // ---- compute: 64 tokens(lanes) x 16 experts over KC ----
        const float* wk = wbase + kc;                 // uniform
        const float* src = buf + lane * LDS_STRIDE;   // this lane's token row

        float cacc[16];
#pragma unroll
        for (int j = 0; j < 16; ++j) cacc[j] = 0.0f;

#pragma unroll 4
        for (int kk = 0; kk < KC; kk += 4) {
            float4 hv = *(const float4*)(src + kk);   // ds_read_b128
#pragma unroll
            for (int j = 0; j < 16; ++j) {
                float4 wv = *(const float4*)(wk + (size_t)j * DIM + kk);  // s_load_dwordx4
                cacc[j] = fmaf(hv.x, wv.x,
                          fmaf(hv.y, wv.y,
                          fmaf(hv.z, wv.z,
                          fmaf(hv.w, wv.w, cacc[j]))));
            }
        }
        // blocked summation (keeps accumulation error ~ numpy pairwise level)
#pragma unroll
        for (int j = 0; j < 16; ++j) acc[j] += cacc[j];
        // no trailing barrier needed: double-buffered; next iter's barrier protects reuse
    }

    // ---- epilogue: logits -> LDS [64][68], then softmax + top2 ----
    __syncthreads();  // all compute reads done before we repurpose LDS
    float* lg = lds;
    const int e0 = wave * 16;
#pragma unroll
    for (int j = 0; j < 16; j += 4) {
        float4 v = make_float4(acc[j], acc[j + 1], acc[j + 2], acc[j + 3]);
        *(float4*)(lg + lane * 68 + e0 + j) = v;
    }
    __syncthreads();

    if (tid < TOKENS) {
        const float* row = lg + tid * 68;
        float m = -INFINITY;
#pragma unroll 8
        for (int e = 0; e < NEXP; ++e) m = fmaxf(m, row[e]);

        float z = 0.0f;
        float b1 = -INFINITY, b2 = -INFINITY;
        int   i1 = 0, i2 = 0;
        for (int e = 0; e < NEXP; ++e) {
            float v = row[e];
            z += expf(v - m);
            if (v > b1) { b2 = b1; i2 = i1; b1 = v; i1 = e; }
            else if (v > b2) { b2 = v; i2 = e; }
        }
        float g1 = expf(b1 - m), g2 = expf(b2 - m);
        float w1 = g1 / z, w2 = g2 / z;       // softmax weights (gathered)
        float s  = w1 + w2 + 1e-9f;           // masked renorm denom, matches ref
        float ow1 = w1 / s, ow2 = w2 / s;

        int t = t0 + tid;
        *(float2*)(out + 2 * t) = make_float2(ow1, ow2);
        // indices written as float32 values (whole out buffer is read back as fp32)
        *(float2*)(out + 2 * n_tokens + 2 * t) = make_float2((float)i1, (float)i2);
    }
}

extern "C" void kernel_launch(void* const* d_in, const int* in_sizes, int n_in,
                              void* d_out, int out_size, void* d_ws, size_t ws_size,
                              hipStream_t stream) {
    const float* h = (const float*)d_in[0];
    const float* W = (const float*)d_in[1];
    float* out = (float*)d_out;
    const int n_tokens = in_sizes[0] / DIM;   // 16384
    dim3 grid(n_tokens / TOKENS);             // 256 blocks
    dim3 block(256);
    topk_gate_kernel<<<grid, block, 0, stream>>>(h, W, out, n_tokens);
}

// Round 2
// 662.759 us; speedup vs baseline: 1.9758x; 1.9758x over previous
//
#include <hip/hip_runtime.h>
#include <math.h>

#define TOKENS 64            // tokens per block (lane = token)
#define DIM 4096             // hidden dim
#define NEXP 64              // experts
#define SPLITS 4             // k-splits
#define KSPAN (DIM / SPLITS) // 1024 k per split
#define KC 64                // k-chunk staged in LDS
#define NCHUNK (KSPAN / KC)  // 16
#define LDS_STRIDE (KC + 4)  // 68: lane stride ≡ 4 mod 32 dwords -> conflict-free b128

// ---------------- Kernel 1: split-K GEMM -> partial logits [s][e][t] --------
// Block: 256 thr = 4 waves; wave w handles experts [w*16, w*16+16); lane = token.
// Grid: 1024 = (s << 8) | token_group  -> 4 blocks/CU, 16 waves/CU.
__global__ __launch_bounds__(256, 4)
void gate_gemm_kernel(const float* __restrict__ h, const float* __restrict__ W,
                      float* __restrict__ partial, int n_tokens) {
    __shared__ float lds[2 * TOKENS * LDS_STRIDE];  // 34816 B -> 4 blocks/CU

    const int tid  = threadIdx.x;
    const int lane = tid & 63;
    const int wave = __builtin_amdgcn_readfirstlane(tid >> 6);
    const int bx   = blockIdx.x;
    const int tg   = bx & 255;   // token group
    const int s    = bx >> 8;    // k-split
    const int t0   = tg * TOKENS;
    const int k0   = s * KSPAN;

    const float* wbase = W + (size_t)wave * 16 * DIM + k0;  // wave-uniform

    float acc[16];
#pragma unroll
    for (int j = 0; j < 16; ++j) acc[j] = 0.0f;

    // staging regs: 64 tok x 64 k = 4096 floats / 256 thr = 4 float4 each
    float4 st[4];
#pragma unroll
    for (int r = 0; r < 4; ++r) {
        int flat = r * 256 + tid;
        int t = flat >> 4, q = flat & 15;        // 16 float4 per 64-float row
        st[r] = *(const float4*)(h + (size_t)(t0 + t) * DIM + k0 + q * 4);
    }

    for (int c = 0; c < NCHUNK; ++c) {
        float* buf = &lds[(c & 1) * TOKENS * LDS_STRIDE];
#pragma unroll
        for (int r = 0; r < 4; ++r) {
            int flat = r * 256 + tid;
            int t = flat >> 4, q = flat & 15;
            *(float4*)(buf + t * LDS_STRIDE + q * 4) = st[r];
        }
        __syncthreads();

        if (c + 1 < NCHUNK) {  // prefetch next chunk while computing
            const int kn = k0 + (c + 1) * KC;
#pragma unroll
            for (int r = 0; r < 4; ++r) {
                int flat = r * 256 + tid;
                int t = flat >> 4, q = flat & 15;
                st[r] = *(const float4*)(h + (size_t)(t0 + t) * DIM + kn + q * 4);
            }
        }

        const float* wk  = wbase + c * KC;             // uniform
        const float* src = buf + lane * LDS_STRIDE;    // this lane's token row

        float cacc[16];
#pragma unroll
        for (int j = 0; j < 16; ++j) cacc[j] = 0.0f;

#pragma unroll 4
        for (int kk = 0; kk < KC; kk += 4) {
            float4 hv = *(const float4*)(src + kk);    // ds_read_b128
#pragma unroll
            for (int j = 0; j < 16; ++j) {
                float4 wv = *(const float4*)(wk + (size_t)j * DIM + kk);
                cacc[j] = fmaf(hv.x, wv.x,
                          fmaf(hv.y, wv.y,
                          fmaf(hv.z, wv.z,
                          fmaf(hv.w, wv.w, cacc[j]))));
            }
        }
#pragma unroll
        for (int j = 0; j < 16; ++j) acc[j] += cacc[j];
        // double-buffered: next iter's barrier protects buffer reuse
    }

    // write partials [s][e][t] -> coalesced dword stores across lanes(tokens)
    const int e0 = wave * 16;
#pragma unroll
    for (int j = 0; j < 16; ++j) {
        partial[((size_t)(s * NEXP + e0 + j)) * n_tokens + t0 + lane] = acc[j];
    }
}

// ---------------- Kernel 2: reduce splits + softmax + top-2 -----------------
__global__ __launch_bounds__(256)
void gate_reduce_kernel(const float* __restrict__ partial,
                        float* __restrict__ out, int n_tokens) {
    const int t = blockIdx.x * 256 + threadIdx.x;
    if (t >= n_tokens) return;

    float logit[NEXP];
#pragma unroll
    for (int e = 0; e < NEXP; ++e) logit[e] = 0.0f;
#pragma unroll
    for (int s = 0; s < SPLITS; ++s) {
#pragma unroll
        for (int e = 0; e < NEXP; ++e)
            logit[e] += partial[((size_t)(s * NEXP + e)) * n_tokens + t];
    }

    float m = -INFINITY;
#pragma unroll
    for (int e = 0; e < NEXP; ++e) m = fmaxf(m, logit[e]);

    float z = 0.0f;
    float b1 = -INFINITY, b2 = -INFINITY;
    int   i1 = 0, i2 = 0;
    for (int e = 0; e < NEXP; ++e) {
        float v = logit[e];
        z += expf(v - m);
        if (v > b1)      { b2 = b1; i2 = i1; b1 = v; i1 = e; }
        else if (v > b2) { b2 = v; i2 = e; }
    }
    float g1 = expf(b1 - m), g2 = expf(b2 - m);
    float w1 = g1 / z, w2 = g2 / z;
    float ssum = w1 + w2 + 1e-9f;
    *(float2*)(out + 2 * t) = make_float2(w1 / ssum, w2 / ssum);
    *(float2*)(out + 2 * n_tokens + 2 * t) = make_float2((float)i1, (float)i2);
}

// ---------------- Fallback: round-1 single kernel (if ws too small) ---------
#define FKC 128
#define FSTRIDE (FKC + 4)
__global__ __launch_bounds__(256, 1)
void topk_gate_fallback(const float* __restrict__ h, const float* __restrict__ W,
                        float* __restrict__ out, int n_tokens) {
    __shared__ float lds[2 * TOKENS * FSTRIDE];
    const int tid  = threadIdx.x;
    const int lane = tid & 63;
    const int wave = __builtin_amdgcn_readfirstlane(tid >> 6);
    const int t0   = blockIdx.x * TOKENS;
    const float* wbase = W + (size_t)wave * 16 * DIM;
    float acc[16];
#pragma unroll
    for (int j = 0; j < 16; ++j) acc[j] = 0.0f;
    float4 st[8];
#pragma unroll
    for (int r = 0; r < 8; ++r) {
        int flat = r * 256 + tid;
        int t = flat >> 5, q = flat & 31;
        st[r] = *(const float4*)(h + (size_t)(t0 + t) * DIM + q * 4);
    }
    const int NC = DIM / FKC;
    for (int c = 0; c < NC; ++c) {
        float* buf = &lds[(c & 1) * TOKENS * FSTRIDE];
#pragma unroll
        for (int r = 0; r < 8; ++r) {
            int flat = r * 256 + tid;
            int t = flat >> 5, q = flat & 31;
            *(float4*)(buf + t * FSTRIDE + q * 4) = st[r];
        }
        __syncthreads();
        if (c + 1 < NC) {
            const int kn = (c + 1) * FKC;
#pragma unroll
            for (int r = 0; r < 8; ++r) {
                int flat = r * 256 + tid;
                int t = flat >> 5, q = flat & 31;
                st[r] = *(const float4*)(h + (size_t)(t0 + t) * DIM + kn + q * 4);
            }
        }
        const float* wk  = wbase + c * FKC;
        const float* src = buf + lane * FSTRIDE;
        float cacc[16];
#pragma unroll
        for (int j = 0; j < 16; ++j) cacc[j] = 0.0f;
#pragma unroll 4
        for (int kk = 0; kk < FKC; kk += 4) {
            float4 hv = *(const float4*)(src + kk);
#pragma unroll
            for (int j = 0; j < 16; ++j) {
                float4 wv = *(const float4*)(wk + (size_t)j * DIM + kk);
                cacc[j] = fmaf(hv.x, wv.x, fmaf(hv.y, wv.y,
                          fmaf(hv.z, wv.z, fmaf(hv.w, wv.w, cacc[j]))));
            }
        }
#pragma unroll
        for (int j = 0; j < 16; ++j) acc[j] += cacc[j];
    }
    __syncthreads();
    float* lg = lds;
    const int e0 = wave * 16;
#pragma unroll
    for (int j = 0; j < 16; j += 4)
        *(float4*)(lg + lane * 68 + e0 + j) =
            make_float4(acc[j], acc[j+1], acc[j+2], acc[j+3]);
    __syncthreads();
    if (tid < TOKENS) {
        const float* row = lg + tid * 68;
        float m = -INFINITY;
        for (int e = 0; e < NEXP; ++e) m = fmaxf(m, row[e]);
        float z = 0.0f, b1 = -INFINITY, b2 = -INFINITY;
        int i1 = 0, i2 = 0;
        for (int e = 0; e < NEXP; ++e) {
            float v = row[e];
            z += expf(v - m);
            if (v > b1)      { b2 = b1; i2 = i1; b1 = v; i1 = e; }
            else if (v > b2) { b2 = v; i2 = e; }
        }
        float g1 = expf(b1 - m), g2 = expf(b2 - m);
        float w1 = g1 / z, w2 = g2 / z;
        float ssum = w1 + w2 + 1e-9f;
        int t = t0 + tid;
        *(float2*)(out + 2 * t) = make_float2(w1 / ssum, w2 / ssum);
        *(float2*)(out + 2 * n_tokens + 2 * t) = make_float2((float)i1, (float)i2);
    }
}

extern "C" void kernel_launch(void* const* d_in, const int* in_sizes, int n_in,
                              void* d_out, int out_size, void* d_ws, size_t ws_size,
                              hipStream_t stream) {
    const float* h = (const float*)d_in[0];
    const float* W = (const float*)d_in[1];
    float* out = (float*)d_out;
    const int n_tokens = in_sizes[0] / DIM;   // 16384

    const size_t need = (size_t)SPLITS * NEXP * n_tokens * sizeof(float); // 16.8 MB
    if (ws_size >= need) {
        float* partial = (float*)d_ws;
        dim3 g1(SPLITS * (n_tokens / TOKENS));  // 1024
        gate_gemm_kernel<<<g1, 256, 0, stream>>>(h, W, partial, n_tokens);
        dim3 g2((n_tokens + 255) / 256);        // 64
        gate_reduce_kernel<<<g2, 256, 0, stream>>>(partial, out, n_tokens);
    } else {
        topk_gate_fallback<<<n_tokens / TOKENS, 256, 0, stream>>>(h, W, out, n_tokens);
    }
}

// Round 3
// 435.351 us; speedup vs baseline: 3.0079x; 1.5224x over previous
//
#include <hip/hip_runtime.h>
#include <math.h>

#define DIM   4096
#define NEXP  64
#define MB    32               // tokens per block
#define KC    128              // k per LDS stage
#define NST   (DIM / KC)       // 32 stages
#define ASTR  (KC + 8)         // halves per LDS row: 272 B -> rows stay 16B-aligned

typedef _Float16 f16x8 __attribute__((ext_vector_type(8)));
typedef _Float16 f16x4 __attribute__((ext_vector_type(4)));
typedef float    f32x4 __attribute__((ext_vector_type(4)));

// ---------------- Kernel 0: W fp32 -> (hi, lo) fp16 planes in ws ------------
__global__ __launch_bounds__(256)
void convert_w_kernel(const float* __restrict__ W,
                      _Float16* __restrict__ wh, _Float16* __restrict__ wl) {
    int i = (blockIdx.x * 256 + threadIdx.x) * 4;
    float4 v = *(const float4*)(W + i);
    _Float16 a0 = (_Float16)v.x, a1 = (_Float16)v.y;
    _Float16 a2 = (_Float16)v.z, a3 = (_Float16)v.w;
    f16x4 hh = {a0, a1, a2, a3};
    f16x4 ll = {(_Float16)(v.x - (float)a0), (_Float16)(v.y - (float)a1),
                (_Float16)(v.z - (float)a2), (_Float16)(v.w - (float)a3)};
    *(f16x4*)(wh + i) = hh;
    *(f16x4*)(wl + i) = ll;
}

// ---------------- Kernel 1: fused fp16-split MFMA gate ----------------------
// Block: 256 thr = 4 waves. wave = (mg = w&1) x (ng = w>>1):
//   tokens [16*mg, +16), experts [32*ng, +32) as 2 n-tiles of 16.
// Grid: n_tokens/32 = 512 blocks -> 2 blocks/CU.
// C = Ahi*Bhi + Ahi*Blo + Alo*Bhi  (fp32-accurate; lo*lo ~1e-7, negligible)
__global__ __launch_bounds__(256, 2)
void gate_mfma_kernel(const float* __restrict__ h,
                      const _Float16* __restrict__ wh,
                      const _Float16* __restrict__ wl,
                      float* __restrict__ out, int n_tokens) {
    __shared__ _Float16 Ah[2][MB][ASTR];   // 17408 B
    __shared__ _Float16 Al[2][MB][ASTR];   // 17408 B
    __shared__ float    lg[MB][NEXP + 4];  //  8704 B   (total ~43.5 KB)

    const int tid  = threadIdx.x;
    const int lane = tid & 63;
    const int wv   = __builtin_amdgcn_readfirstlane(tid >> 6);
    const int mg   = wv & 1;
    const int ng   = wv >> 1;
    const int t0   = blockIdx.x * MB;
    const int l15  = lane & 15;
    const int quad = lane >> 4;

    // B fragment row pointers: W stored [expert][k] = N x K row-major (gemm_bt style)
    const _Float16* bh0 = wh + (size_t)(32 * ng + l15) * DIM + 8 * quad;
    const _Float16* bh1 = bh0 + (size_t)16 * DIM;
    const _Float16* bl0 = wl + (size_t)(32 * ng + l15) * DIM + 8 * quad;
    const _Float16* bl1 = bl0 + (size_t)16 * DIM;

    f32x4 acc0 = {0.f, 0.f, 0.f, 0.f};
    f32x4 acc1 = {0.f, 0.f, 0.f, 0.f};

    // staging: 32 tok x 128 k fp32 = 1024 float4 / 256 thr = 4 per thread
    float4 st[4];
    int s_t[4], s_q[4];
#pragma unroll
    for (int r = 0; r < 4; ++r) {
        int flat = r * 256 + tid;
        s_t[r] = flat >> 5;          // token row 0..31
        s_q[r] = flat & 31;          // float4 index within row (k = 4q)
        st[r] = *(const float4*)(h + (size_t)(t0 + s_t[r]) * DIM + 4 * s_q[r]);
    }

    for (int c = 0; c < NST; ++c) {
        const int buf = c & 1;
        // convert fp32 -> hi/lo fp16, write to LDS
#pragma unroll
        for (int r = 0; r < 4; ++r) {
            float4 v = st[r];
            _Float16 a0 = (_Float16)v.x, a1 = (_Float16)v.y;
            _Float16 a2 = (_Float16)v.z, a3 = (_Float16)v.w;
            f16x4 hh = {a0, a1, a2, a3};
            f16x4 ll = {(_Float16)(v.x - (float)a0), (_Float16)(v.y - (float)a1),
                        (_Float16)(v.z - (float)a2), (_Float16)(v.w - (float)a3)};
            *(f16x4*)(&Ah[buf][s_t[r]][4 * s_q[r]]) = hh;
            *(f16x4*)(&Al[buf][s_t[r]][4 * s_q[r]]) = ll;
        }
        __syncthreads();

        if (c + 1 < NST) {  // prefetch next stage (overlaps MFMA below)
            const int kn = (c + 1) * KC;
#pragma unroll
            for (int r = 0; r < 4; ++r)
                st[r] = *(const float4*)(h + (size_t)(t0 + s_t[r]) * DIM + kn + 4 * s_q[r]);
        }

        const _Float16* arow_h = &Ah[buf][16 * mg + l15][8 * quad];
        const _Float16* arow_l = &Al[buf][16 * mg + l15][8 * quad];
        const size_t kb = (size_t)c * KC;
#pragma unroll
        for (int s = 0; s < 4; ++s) {
            f16x8 af_h = *(const f16x8*)(arow_h + 32 * s);
            f16x8 af_l = *(const f16x8*)(arow_l + 32 * s);
            f16x8 b0h  = *(const f16x8*)(bh0 + kb + 32 * s);
            f16x8 b1h  = *(const f16x8*)(bh1 + kb + 32 * s);
            f16x8 b0l  = *(const f16x8*)(bl0 + kb + 32 * s);
            f16x8 b1l  = *(const f16x8*)(bl1 + kb + 32 * s);
            acc0 = __builtin_amdgcn_mfma_f32_16x16x32_f16(af_h, b0h, acc0, 0, 0, 0);
            acc0 = __builtin_amdgcn_mfma_f32_16x16x32_f16(af_h, b0l, acc0, 0, 0, 0);
            acc0 = __builtin_amdgcn_mfma_f32_16x16x32_f16(af_l, b0h, acc0, 0, 0, 0);
            acc1 = __builtin_amdgcn_mfma_f32_16x16x32_f16(af_h, b1h, acc1, 0, 0, 0);
            acc1 = __builtin_amdgcn_mfma_f32_16x16x32_f16(af_h, b1l, acc1, 0, 0, 0);
            acc1 = __builtin_amdgcn_mfma_f32_16x16x32_f16(af_l, b1h, acc1, 0, 0, 0);
        }
        // double-buffered: next iteration's barrier protects buffer reuse
    }

    // ---- epilogue: C/D layout col=lane&15 (expert), row=quad*4+r (token) ----
#pragma unroll
    for (int r = 0; r < 4; ++r) {
        lg[16 * mg + 4 * quad + r][32 * ng + l15]      = acc0[r];
        lg[16 * mg + 4 * quad + r][32 * ng + 16 + l15] = acc1[r];
    }
    __syncthreads();

    if (tid < MB) {
        const float* row = lg[tid];
        float m = -INFINITY;
#pragma unroll 8
        for (int e = 0; e < NEXP; ++e) m = fmaxf(m, row[e]);
        float z = 0.0f, b1 = -INFINITY, b2 = -INFINITY;
        int i1 = 0, i2 = 0;
        for (int e = 0; e < NEXP; ++e) {
            float v = row[e];
            z += expf(v - m);
            if (v > b1)      { b2 = b1; i2 = i1; b1 = v; i1 = e; }
            else if (v > b2) { b2 = v; i2 = e; }
        }
        float g1 = expf(b1 - m), g2 = expf(b2 - m);
        float w1 = g1 / z, w2 = g2 / z;
        float ssum = w1 + w2 + 1e-9f;
        int t = t0 + tid;
        *(float2*)(out + 2 * t) = make_float2(w1 / ssum, w2 / ssum);
        *(float2*)(out + 2 * n_tokens + 2 * t) = make_float2((float)i1, (float)i2);
    }
}

extern "C" void kernel_launch(void* const* d_in, const int* in_sizes, int n_in,
                              void* d_out, int out_size, void* d_ws, size_t ws_size,
                              hipStream_t stream) {
    const float* h = (const float*)d_in[0];
    const float* W = (const float*)d_in[1];
    float* out = (float*)d_out;
    const int n_tokens = in_sizes[0] / DIM;       // 16384

    _Float16* wh = (_Float16*)d_ws;               // 512 KB
    _Float16* wl = wh + (size_t)NEXP * DIM;       // 512 KB (ws >= 16.8 MB verified R2)

    convert_w_kernel<<<(NEXP * DIM) / (256 * 4), 256, 0, stream>>>(W, wh, wl);
    gate_mfma_kernel<<<n_tokens / MB, 256, 0, stream>>>(h, wh, wl, out, n_tokens);
}

// Round 4
// 371.607 us; speedup vs baseline: 3.5238x; 1.1715x over previous
//
#include <hip/hip_runtime.h>
#include <math.h>

#define DIM   4096
#define NEXP  64
#define MB    32               // tokens per block
#define KC    128              // k per LDS stage (elements)
#define NST   (DIM / KC)       // 32 stages

typedef _Float16 f16x8 __attribute__((ext_vector_type(8)));
typedef _Float16 f16x4 __attribute__((ext_vector_type(4)));
typedef float    f32x4 __attribute__((ext_vector_type(4)));

// ---- Kernel 0: pack W -> fp16 hi/lo planes in MFMA B-fragment order --------
// wp[nt(4)][ck(128)][lane(64)][j(8)]; lane = quad*16 + n; element = W[nt*16+n][ck*32+quad*8+j]
// A B-frag load is then base + lane*16B: one fully-coalesced 1KB transaction.
__global__ __launch_bounds__(256)
void pack_w_kernel(const float* __restrict__ W,
                   _Float16* __restrict__ wph, _Float16* __restrict__ wpl) {
    const int flat = blockIdx.x * 256 + threadIdx.x;   // nt*8192 + ck*64 + lane
    const int lane = flat & 63;
    const int ck   = (flat >> 6) & 127;
    const int nt   = flat >> 13;
    const int e    = nt * 16 + (lane & 15);
    const int k0   = ck * 32 + (lane >> 4) * 8;
    const float* src = W + ((size_t)e << 12) + k0;
    float4 v0 = *(const float4*)(src);
    float4 v1 = *(const float4*)(src + 4);
    float vv[8] = {v0.x, v0.y, v0.z, v0.w, v1.x, v1.y, v1.z, v1.w};
    f16x8 hi, lo;
#pragma unroll
    for (int i = 0; i < 8; ++i) {
        _Float16 hh = (_Float16)vv[i];
        hi[i] = hh;
        lo[i] = (_Float16)(vv[i] - (float)hh);   // Sterbenz-exact residual
    }
    *(f16x8*)(wph + (size_t)flat * 8) = hi;      // coalesced 16B/lane stores
    *(f16x8*)(wpl + (size_t)flat * 8) = lo;
}

// ---- Kernel 1: fused gate. wave = n-group(16 experts) x all 32 tokens ------
// C = Ah*Bh + Al*Bh + Ah*Bl (fp32-accurate). B register-double-buffered one
// stage ahead; A LDS XOR-swizzled (block ^ row&15) -> conflict-free, no pad.
__global__ __launch_bounds__(256, 3)
void gate_mfma_kernel(const float* __restrict__ h,
                      const _Float16* __restrict__ wph,
                      const _Float16* __restrict__ wpl,
                      float* __restrict__ out, int n_tokens) {
    __shared__ _Float16 Ah[2][MB * KC];     // 16 KB
    __shared__ _Float16 Al[2][MB * KC];     // 16 KB
    __shared__ float    lg[MB][NEXP + 4];   // 8.7 KB  -> total 41.4 KB, 3 blk/CU

    const int tid  = threadIdx.x;
    const int lane = tid & 63;
    const int wv   = __builtin_amdgcn_readfirstlane(tid >> 6);  // n-group 0..3
    const int l15  = lane & 15;
    const int quad = lane >> 4;
    const int t0   = blockIdx.x * MB;

    // h staging map: flat = r*256+tid -> token row t, float4 index q (coalesced)
    int s_t[4], s_q[4];
    float4 st[4];
#pragma unroll
    for (int r = 0; r < 4; ++r) {
        int flat = r * 256 + tid;
        s_t[r] = flat >> 5;
        s_q[r] = flat & 31;
        st[r]  = *(const float4*)(h + (size_t)(t0 + s_t[r]) * DIM + 4 * s_q[r]);
    }

    // B fragment base for this wave's n-group; chunk stride = 512 halves
    const _Float16* bph = wph + ((size_t)(wv * 128) * 64 + lane) * 8;
    const _Float16* bpl = wpl + ((size_t)(wv * 128) * 64 + lane) * 8;
    f16x8 Bh[2][4], Bl[2][4];
#pragma unroll
    for (int s = 0; s < 4; ++s) {
        Bh[0][s] = *(const f16x8*)(bph + s * 512);
        Bl[0][s] = *(const f16x8*)(bpl + s * 512);
    }

    f32x4 acc0 = {0.f, 0.f, 0.f, 0.f};   // tokens 0..15
    f32x4 acc1 = {0.f, 0.f, 0.f, 0.f};   // tokens 16..31

#pragma unroll 2
    for (int c = 0; c < NST; ++c) {
        const int buf = c & 1;
        // convert fp32 -> hi/lo, swizzled LDS write (b64, 2-way max = free)
#pragma unroll
        for (int r = 0; r < 4; ++r) {
            float4 v = st[r];
            _Float16 a0 = (_Float16)v.x, a1 = (_Float16)v.y,
                     a2 = (_Float16)v.z, a3 = (_Float16)v.w;
            f16x4 hh = {a0, a1, a2, a3};
            f16x4 ll = {(_Float16)(v.x - (float)a0), (_Float16)(v.y - (float)a1),
                        (_Float16)(v.z - (float)a2), (_Float16)(v.w - (float)a3)};
            int t = s_t[r], q = s_q[r];
            int addr = t * KC + (((q >> 1) ^ (t & 15)) << 3) + ((q & 1) << 2);
            *(f16x4*)(&Ah[buf][addr]) = hh;
            *(f16x4*)(&Al[buf][addr]) = ll;
        }
        __syncthreads();

        if (c + 1 < NST) {   // prefetch h + B for next stage (hidden under MFMA)
            const int kn = (c + 1) * KC;
#pragma unroll
            for (int r = 0; r < 4; ++r)
                st[r] = *(const float4*)(h + (size_t)(t0 + s_t[r]) * DIM + kn + 4 * s_q[r]);
            const int nb = (c + 1) & 1;
            const size_t coff = (size_t)(c + 1) * 4 * 512;
#pragma unroll
            for (int s = 0; s < 4; ++s) {
                Bh[nb][s] = *(const f16x8*)(bph + coff + s * 512);
                Bl[nb][s] = *(const f16x8*)(bpl + coff + s * 512);
            }
        }

#pragma unroll
        for (int s = 0; s < 4; ++s) {
            const int pb = (((4 * s + quad) ^ l15) << 3);   // swizzled 16B block
            f16x8 a0h = *(const f16x8*)(&Ah[buf][l15 * KC + pb]);
            f16x8 a1h = *(const f16x8*)(&Ah[buf][(16 + l15) * KC + pb]);
            f16x8 a0l = *(const f16x8*)(&Al[buf][l15 * KC + pb]);
            f16x8 a1l = *(const f16x8*)(&Al[buf][(16 + l15) * KC + pb]);
            f16x8 bh = Bh[buf][s], bl = Bl[buf][s];
            acc0 = __builtin_amdgcn_mfma_f32_16x16x32_f16(a0h, bh, acc0, 0, 0, 0);
            acc1 = __builtin_amdgcn_mfma_f32_16x16x32_f16(a1h, bh, acc1, 0, 0, 0);
            acc0 = __builtin_amdgcn_mfma_f32_16x16x32_f16(a0l, bh, acc0, 0, 0, 0);
            acc1 = __builtin_amdgcn_mfma_f32_16x16x32_f16(a1l, bh, acc1, 0, 0, 0);
            acc0 = __builtin_amdgcn_mfma_f32_16x16x32_f16(a0h, bl, acc0, 0, 0, 0);
            acc1 = __builtin_amdgcn_mfma_f32_16x16x32_f16(a1h, bl, acc1, 0, 0, 0);
        }
        // double-buffered: next iteration's barrier protects buffer reuse
    }

    // ---- epilogue: C/D layout col(expert)=lane&15, row(token)=quad*4+r ----
#pragma unroll
    for (int r = 0; r < 4; ++r) {
        lg[4 * quad + r][wv * 16 + l15]      = acc0[r];
        lg[16 + 4 * quad + r][wv * 16 + l15] = acc1[r];
    }
    __syncthreads();

    if (tid < MB) {
        const float* row = lg[tid];
        float m = -INFINITY;
#pragma unroll 8
        for (int e = 0; e < NEXP; ++e) m = fmaxf(m, row[e]);
        float z = 0.0f, b1 = -INFINITY, b2 = -INFINITY;
        int i1 = 0, i2 = 0;
        for (int e = 0; e < NEXP; ++e) {
            float v = row[e];
            z += expf(v - m);
            if (v > b1)      { b2 = b1; i2 = i1; b1 = v; i1 = e; }
            else if (v > b2) { b2 = v; i2 = e; }
        }
        float g1 = expf(b1 - m), g2 = expf(b2 - m);
        float w1 = g1 / z, w2 = g2 / z;
        float ssum = w1 + w2 + 1e-9f;
        int t = t0 + tid;
        *(float2*)(out + 2 * t) = make_float2(w1 / ssum, w2 / ssum);
        *(float2*)(out + 2 * n_tokens + 2 * t) = make_float2((float)i1, (float)i2);
    }
}

extern "C" void kernel_launch(void* const* d_in, const int* in_sizes, int n_in,
                              void* d_out, int out_size, void* d_ws, size_t ws_size,
                              hipStream_t stream) {
    const float* h = (const float*)d_in[0];
    const float* W = (const float*)d_in[1];
    float* out = (float*)d_out;
    const int n_tokens = in_sizes[0] / DIM;        // 16384

    _Float16* wph = (_Float16*)d_ws;               // 512 KB packed hi
    _Float16* wpl = wph + (size_t)NEXP * DIM;      // 512 KB packed lo

    pack_w_kernel<<<(NEXP * DIM / 8) / 256, 256, 0, stream>>>(W, wph, wpl);
    gate_mfma_kernel<<<n_tokens / MB, 256, 0, stream>>>(h, wph, wpl, out, n_tokens);
}